// Round 9
// baseline (443.241 us; speedup 1.0000x reference)
//
#include <hip/hip_runtime.h>

#define NN 50000
#define NE 600000
#define DD 128
#define CAP 64
#define GRID ((NN + 63) / 64)                   // 782 blocks; 4/CU static -> 1024 co-resident

typedef __attribute__((ext_vector_type(8))) short s16x8;   // 8 bf16 (4 VGPRs)
typedef __attribute__((ext_vector_type(4))) float f32x4;   // MFMA accumulator

// d_ws layout (bytes):
//   [0, 200000)      : int cnt[NN]               \ both zeroed by the single
//   [200064, 200068) : uint barrier               / memset node each launch
//   [SLOT_OFF, +6.4M): ushort slots[NN*CAP]
//   [WPACK_OFF,+192K): ushort wpack[3*8*8*512]   (B-fragment-packed bf16 weights)
//   [NBF_OFF, +12.8M): ushort nbf[NN*DD]         (bf16 copy of nodes)
#define CNT_BYTES   (256 * 1024)
#define BAR_OFF     200064
#define SLOT_OFF    CNT_BYTES
#define SLOT_BYTES  ((size_t)NN * CAP * 2)
#define WPACK_OFF   (SLOT_OFF + SLOT_BYTES)
#define WPACK_N     (3 * 8 * 8 * 512)           // 98304 ushort = 192 KB
#define WPACK_BYTES ((size_t)WPACK_N * 2)
#define NBF_OFF     (WPACK_OFF + WPACK_BYTES)   // 16B-aligned

__device__ __forceinline__ unsigned short f2bf(float f) {   // RNE fp32->bf16
    unsigned int u = __float_as_uint(f);
    unsigned int r = (u + 0x7fffu + ((u >> 16) & 1u)) >> 16;
    return (unsigned short)r;
}
__device__ __forceinline__ float bf2f(unsigned short h) {
    return __uint_as_float(((unsigned int)h) << 16);
}
__device__ __forceinline__ void accum8(float* x, uint4 v, float msk) {
    x[0] = fmaf(__uint_as_float(v.x << 16),          msk, x[0]);
    x[1] = fmaf(__uint_as_float(v.x & 0xffff0000u),  msk, x[1]);
    x[2] = fmaf(__uint_as_float(v.y << 16),          msk, x[2]);
    x[3] = fmaf(__uint_as_float(v.y & 0xffff0000u),  msk, x[3]);
    x[4] = fmaf(__uint_as_float(v.z << 16),          msk, x[4]);
    x[5] = fmaf(__uint_as_float(v.z & 0xffff0000u),  msk, x[5]);
    x[6] = fmaf(__uint_as_float(v.w << 16),          msk, x[6]);
    x[7] = fmaf(__uint_as_float(v.w & 0xffff0000u),  msk, x[7]);
}

// ======== mega kernel: prep (grid-strided) -> SW grid barrier -> gather+GEMM ========
__global__ __launch_bounds__(256, 4) void mega_k(
    const float* __restrict__ nodes,
    const int* __restrict__ adj,
    int* __restrict__ cnt,
    unsigned int* __restrict__ barrier,
    unsigned short* __restrict__ slots,
    unsigned short* __restrict__ wp,
    unsigned short* __restrict__ nbf,
    const float* __restrict__ bias,
    const float* __restrict__ Wr, const float* __restrict__ Wz,
    const float* __restrict__ Wt,
    const float* __restrict__ br, const float* __restrict__ bz,
    const float* __restrict__ bt,
    float* __restrict__ out)
{
    // ---- Phase 0: prep, distributed across the whole grid (coalesced strides)
    {
        const int gtid = blockIdx.x * 256 + threadIdx.x;
        const int nthr = GRID * 256;                       // 200192
        // fill buckets: 3 strided passes cover 600K edges
#pragma unroll
        for (int i = 0; i < 3; ++i) {
            int e = gtid + i * nthr;
            if (e < NE) {
                int d = adj[e];
                int s = adj[NE + e];
                int pos = atomicAdd(&cnt[d], 1);
                if (pos < CAP) slots[(size_t)d * CAP + pos] = (unsigned short)s;
                // pos >= CAP: cnt[d] > CAP signals the full-scan path below
            }
        }
        // pack weights into B-fragment order (one element per thread)
        if (gtid < WPACK_N) {
            int t = gtid;
            int j  = t & 7;
            int l  = (t >> 3) & 63;
            int kt = (t >> 9) & 7;
            int ct = (t >> 12) & 7;
            int g  = t >> 15;
            int k   = kt * 32 + ((l >> 4) & 3) * 8 + j;
            int col = ct * 16 + (l & 15);
            const float* W = (g == 0) ? Wr : (g == 1) ? Wz : Wt;
            wp[t] = f2bf(W[k * DD + col]);
        }
        // nodes -> bf16 (4 x uint4 per thread, strided/coalesced)
#pragma unroll
        for (int i = 0; i < 4; ++i) {
            int t = gtid + i * nthr;
            if (t < NN * DD / 8) {
                const float4* s4 = (const float4*)nodes + (size_t)t * 2;
                float4 a = s4[0], c4 = s4[1];
                uint4 o;
                o.x = (unsigned)f2bf(a.x)  | ((unsigned)f2bf(a.y)  << 16);
                o.y = (unsigned)f2bf(a.z)  | ((unsigned)f2bf(a.w)  << 16);
                o.z = (unsigned)f2bf(c4.x) | ((unsigned)f2bf(c4.y) << 16);
                o.w = (unsigned)f2bf(c4.z) | ((unsigned)f2bf(c4.w) << 16);
                ((uint4*)nbf)[t] = o;
            }
        }
    }
    // ---- software grid barrier (all 782 blocks are co-resident: LDS 33.8KB
    // -> exactly 4 blocks/CU x 256 CU = 1024 slots; VGPR<=128, 16 waves/CU)
    __threadfence();                 // device-scope release of prep writes
    __syncthreads();                 // whole block's prep done before arrival
    if (threadIdx.x == 0) {
        __hip_atomic_fetch_add(barrier, 1u, __ATOMIC_ACQ_REL, __HIP_MEMORY_SCOPE_AGENT);
        while (__hip_atomic_load(barrier, __ATOMIC_ACQUIRE, __HIP_MEMORY_SCOPE_AGENT)
               < (unsigned)GRID) {
            __builtin_amdgcn_s_sleep(8);
        }
    }
    __syncthreads();
    __threadfence();                 // acquire ordering for all threads

    // ---- fused body (round-7 verified structure, unchanged) ----
    // X[row][0:128]=s (bf16) -> later r*ph; X[row][128:256]=ph (bf16, kept); +8 pad
    __shared__ unsigned short X[64][264];       // 33.8 KB (only LDS array)
    const int tid  = threadIdx.x;
    const int w    = tid >> 6;                  // wave id: owns rows w*16..w*16+15
    const int l    = tid & 63;
    const int row0 = blockIdx.x * 64;
    const int q    = l >> 4;                    // quarter-wave id
    const int li   = l & 15;                    // lane in quarter: channels 8li..8li+7

    // ---- Phase A: 2-deep pipelined gather + softmax, stage bf16 [s|ph] in LDS
    {
        const float4 bb0 = *(const float4*)(bias + 8 * li);
        const float4 bb1 = *(const float4*)(bias + 8 * li + 4);
        int rown  = row0 + (w << 4) + li;
        int c_all = cnt[rown < NN ? rown : 0];

        unsigned short sraw[2];                 // pending slot loads (rows j+1, j+2)
        uint4 vg[2][4]; float mg[2][4];         // pending gathers (rows j, j+1)
        uint4 phg[2];                           // pending ph loads
        int   slotm[2], cj[2];

        // prologue: slot loads for rows 0,1; gathers for row 0
        {
            int g0 = row0 + (w << 4);
            int gc0 = g0 < NN ? g0 : 0;
            int gc1 = (g0 + 1) < NN ? (g0 + 1) : 0;
            sraw[0] = slots[(size_t)gc0 * CAP + l];
            sraw[1] = slots[(size_t)gc1 * CAP + l];
            cj[0] = __shfl(c_all, 0);
            slotm[0] = (l < cj[0]) ? (int)sraw[0] : 0;
            if (q == 1) phg[0] = *(const uint4*)(nbf + (size_t)gc0 * DD + 8 * li);
#pragma unroll
            for (int i = 0; i < 4; ++i) {
                int sp = i * 4 + q;
                int s0 = __shfl(slotm[0], sp);
                vg[0][i] = *(const uint4*)(nbf + (size_t)s0 * DD + 8 * li);
                mg[0][i] = (sp < cj[0]) ? 1.f : 0.f;
            }
        }

#pragma unroll
        for (int j = 0; j < 16; ++j) {
            const int p = j & 1, pn = p ^ 1;
            // issue slot load for row j+2
            unsigned short snew = 0;
            if (j + 2 < 16) {
                int g2 = row0 + (w << 4) + j + 2;
                int gc2 = g2 < NN ? g2 : 0;
                snew = slots[(size_t)gc2 * CAP + l];
            }
            // issue gathers for row j+1 (slot load issued 2 iters ago)
            if (j + 1 < 16) {
                int g1 = row0 + (w << 4) + j + 1;
                int gc1 = g1 < NN ? g1 : 0;
                cj[pn] = __shfl(c_all, j + 1);
                slotm[pn] = (l < cj[pn]) ? (int)sraw[pn] : 0;
                if (q == 1) phg[pn] = *(const uint4*)(nbf + (size_t)gc1 * DD + 8 * li);
#pragma unroll
                for (int i = 0; i < 4; ++i) {
                    int sp = i * 4 + q;
                    int s0 = __shfl(slotm[pn], sp);
                    vg[pn][i] = *(const uint4*)(nbf + (size_t)s0 * DD + 8 * li);
                    mg[pn][i] = (sp < cj[pn]) ? 1.f : 0.f;
                }
            }
            // ---- combine row j
            int lr   = (w << 4) + j;
            int grow = row0 + lr;
            int c    = cj[p];
            float x[8];
#pragma unroll
            for (int i = 0; i < 8; ++i) x[i] = 0.f;
            if (c <= CAP) {
#pragma unroll
                for (int i = 0; i < 4; ++i) accum8(x, vg[p][i], mg[p][i]);
                for (int jj = 16; jj < c; jj += 16) {        // deg>16 tail (~10% rows)
                    uint4 v[4]; float msk[4];
#pragma unroll
                    for (int i = 0; i < 4; ++i) {
                        int sp = jj + i * 4 + q;
                        int s0 = __shfl(slotm[p], sp & 63);
                        v[i] = *(const uint4*)(nbf + (size_t)s0 * DD + 8 * li);
                        msk[i] = (sp < c) ? 1.f : 0.f;
                    }
#pragma unroll
                    for (int i = 0; i < 4; ++i) accum8(x, v[i], msk[i]);
                }
            } else {
                // overflow (prob ~0): full edge scan, matches round-robin over quarters
                int mi = 0;
                for (int base = 0; base < NE; base += 64) {
                    int e  = base + l;
                    int d  = (e < NE) ? adj[e] : -1;
                    int sv = (e < NE) ? adj[NE + e] : 0;
                    unsigned long long m = __ballot(d == grow);
                    while (m) {
                        int bpos = __ffsll((unsigned long long)m) - 1;
                        m &= m - 1;
                        int s0 = __shfl(sv, bpos);
                        if ((mi & 3) == q) {
                            uint4 v = *(const uint4*)(nbf + (size_t)s0 * DD + 8 * li);
                            accum8(x, v, 1.f);
                        }
                        ++mi;
                    }
                }
            }
            // combine quarter partial sums, add bias
#pragma unroll
            for (int i = 0; i < 8; ++i) {
                x[i] += __shfl_xor(x[i], 16);
                x[i] += __shfl_xor(x[i], 32);
            }
            x[0] += bb0.x; x[1] += bb0.y; x[2] += bb0.z; x[3] += bb0.w;
            x[4] += bb1.x; x[5] += bb1.y; x[6] += bb1.z; x[7] += bb1.w;
            // softmax over 128 channels (8/lane x 16 lanes, replicated across quarters)
            float mx = x[0];
#pragma unroll
            for (int i = 1; i < 8; ++i) mx = fmaxf(mx, x[i]);
#pragma unroll
            for (int o = 1; o < 16; o <<= 1) mx = fmaxf(mx, __shfl_xor(mx, o));
            float e8[8], sm = 0.f;
#pragma unroll
            for (int i = 0; i < 8; ++i) { e8[i] = __expf(x[i] - mx); sm += e8[i]; }
#pragma unroll
            for (int o = 1; o < 16; o <<= 1) sm += __shfl_xor(sm, o);
            float inv = 1.f / sm;
            if (q == 0) {
                uint4 u;
                u.x = (unsigned)f2bf(e8[0] * inv) | ((unsigned)f2bf(e8[1] * inv) << 16);
                u.y = (unsigned)f2bf(e8[2] * inv) | ((unsigned)f2bf(e8[3] * inv) << 16);
                u.z = (unsigned)f2bf(e8[4] * inv) | ((unsigned)f2bf(e8[5] * inv) << 16);
                u.w = (unsigned)f2bf(e8[6] * inv) | ((unsigned)f2bf(e8[7] * inv) << 16);
                *(uint4*)&X[lr][8 * li] = u;
            } else if (q == 1) {
                *(uint4*)&X[lr][128 + 8 * li] = phg[p];
            }
            sraw[p] = snew;     // row j+2 has parity p
        }
    }
    // NO __syncthreads: each wave reads only the 16 rows it just wrote.

    // ---- Phase B: MFMA GEMMs. Wave w owns row tile rt=w.
    const int rbase  = w * 16;
    const int mrow   = l & 15;      // A-frag row within tile
    const int quad   = l >> 4;      // A/B-frag k-quad
    const int col_in = l & 15;      // C/D col within tile
    const int rq     = l >> 4;      // C/D row quad

    s16x8 a[8];                      // A-frags for K=256 (8 x 32)
#pragma unroll
    for (int kt = 0; kt < 8; ++kt)
        a[kt] = *(const s16x8*)&X[rbase + mrow][kt * 32 + quad * 8];

    const s16x8* wp8 = (const s16x8*)wp;
    float zv[8][4];

    // r and z over all 8 col-tiles; write r*ph into the (dead) s-half of X,
    // preserving original ph in the ph-half for the epilogue.
#pragma unroll
    for (int ct = 0; ct < 8; ++ct) {
        int c = ct * 16 + col_in;
        float brv = br[c], bzv = bz[c];
        f32x4 ar = {brv, brv, brv, brv};
        f32x4 az = {bzv, bzv, bzv, bzv};
#pragma unroll
        for (int kt = 0; kt < 8; ++kt) {
            s16x8 bfr = wp8[((0 * 8 + ct) * 8 + kt) * 64 + l];
            s16x8 bfz = wp8[((1 * 8 + ct) * 8 + kt) * 64 + l];
            ar = __builtin_amdgcn_mfma_f32_16x16x32_bf16(a[kt], bfr, ar, 0, 0, 0);
            az = __builtin_amdgcn_mfma_f32_16x16x32_bf16(a[kt], bfz, az, 0, 0, 0);
        }
#pragma unroll
        for (int i = 0; i < 4; ++i) {
            float rr = 1.f / (1.f + __expf(-ar[i]));
            zv[ct][i] = 1.f / (1.f + __expf(-az[i]));
            int lr = rbase + rq * 4 + i;
            float ph = bf2f(X[lr][128 + c]);
            X[lr][c] = f2bf(rr * ph);             // same-wave rows only; s-half is dead
        }
    }

    // reload A-frags kt=4..7 (r*ph) from the s-half
#pragma unroll
    for (int kt = 4; kt < 8; ++kt)
        a[kt] = *(const s16x8*)&X[rbase + mrow][(kt - 4) * 32 + quad * 8];

    // t GEMM + epilogue
#pragma unroll
    for (int ct = 0; ct < 8; ++ct) {
        int c = ct * 16 + col_in;
        float btv = bt[c];
        f32x4 at = {btv, btv, btv, btv};
#pragma unroll
        for (int kt = 0; kt < 8; ++kt) {
            s16x8 bft = wp8[((2 * 8 + ct) * 8 + kt) * 64 + l];
            at = __builtin_amdgcn_mfma_f32_16x16x32_bf16(a[kt], bft, at, 0, 0, 0);
        }
#pragma unroll
        for (int i = 0; i < 4; ++i) {
            int lr   = rbase + rq * 4 + i;
            int grow = row0 + lr;
            if (grow < NN) {
                float hh = tanhf(at[i]);
                float z  = zv[ct][i];
                float ph = bf2f(X[lr][128 + c]);  // original ph (bf16), preserved
                out[(size_t)grow * DD + c] = (1.f - z) * ph + z * hh;
            }
        }
    }
}

extern "C" void kernel_launch(void* const* d_in, const int* in_sizes, int n_in,
                              void* d_out, int out_size, void* d_ws, size_t ws_size,
                              hipStream_t stream) {
    const float* nodes = (const float*)d_in[0];
    const int*   adj   = (const int*)d_in[1];
    const float* bias  = (const float*)d_in[2];
    const float* Wr    = (const float*)d_in[3];
    const float* br    = (const float*)d_in[4];
    const float* Wz    = (const float*)d_in[5];
    const float* bz    = (const float*)d_in[6];
    const float* Wt    = (const float*)d_in[7];
    const float* bt    = (const float*)d_in[8];
    float* out = (float*)d_out;

    char* ws = (char*)d_ws;
    int*            cnt   = (int*)ws;
    unsigned int*   bar   = (unsigned int*)(ws + BAR_OFF);
    unsigned short* slots = (unsigned short*)(ws + SLOT_OFF);
    unsigned short* wpack = (unsigned short*)(ws + WPACK_OFF);
    unsigned short* nbf   = (unsigned short*)(ws + NBF_OFF);

    // one memset zeroes both cnt[] and the barrier counter
    hipMemsetAsync(ws, 0, CNT_BYTES, stream);

    // Reference never updates prior_h inside its loop -> all 4 steps identical;
    // one propagation step suffices.
    mega_k<<<GRID, 256, 0, stream>>>(nodes, adj, cnt, bar, slots, wpack, nbf,
                                     bias, Wr, Wz, Wt, br, bz, bt, out);
}

// Round 10
// 196.812 us; speedup vs baseline: 2.2521x; 2.2521x over previous
//
#include <hip/hip_runtime.h>

#define NN 50000
#define NE 600000
#define DD 128
#define CAP 64
#define CSTR 32          // cnt stride in ints: one 128B line per node (atomic contention fix)

typedef __attribute__((ext_vector_type(8))) short s16x8;   // 8 bf16 (4 VGPRs)
typedef __attribute__((ext_vector_type(4))) float f32x4;   // MFMA accumulator

// d_ws layout (bytes):
//   [0, 6.4M)        : int cnt[NN*CSTR]  (128B/node; memset to 0 each launch)
//   [SLOT_OFF, +6.4M): ushort slots[NN*CAP]
//   [WPACK_OFF,+192K): ushort wpack[3*8*8*512]   (B-fragment-packed bf16 weights)
//   [NBF_OFF, +12.8M): ushort nbf[NN*DD]         (bf16 copy of nodes)
// total ~25.8 MB (ws_size >= 27.4 MB demonstrated in round 3)
#define CNT_BYTES   ((size_t)NN * CSTR * 4)     // 6,400,000
#define SLOT_OFF    CNT_BYTES
#define SLOT_BYTES  ((size_t)NN * CAP * 2)      // 6,400,000
#define WPACK_OFF   (SLOT_OFF + SLOT_BYTES)
#define WPACK_N     (3 * 8 * 8 * 512)           // 98304 ushort = 192 KB
#define WPACK_BYTES ((size_t)WPACK_N * 2)
#define NBF_OFF     (WPACK_OFF + WPACK_BYTES)   // 16B-aligned

#define FILL_BLOCKS ((NE + 1023) / 1024)        // 586 (4 edges/thread)
#define FILL_T      (FILL_BLOCKS * 256)         // 150016
#define CONV_BLOCKS (WPACK_N / 256)             // 384
#define NBF_BLOCKS  ((NN * DD / 8) / 256)       // 3125

__device__ __forceinline__ unsigned short f2bf(float f) {   // RNE fp32->bf16
    unsigned int u = __float_as_uint(f);
    unsigned int r = (u + 0x7fffu + ((u >> 16) & 1u)) >> 16;
    return (unsigned short)r;
}
__device__ __forceinline__ float bf2f(unsigned short h) {
    return __uint_as_float(((unsigned int)h) << 16);
}
__device__ __forceinline__ void accum8(float* x, uint4 v, float msk) {
    x[0] = fmaf(__uint_as_float(v.x << 16),          msk, x[0]);
    x[1] = fmaf(__uint_as_float(v.x & 0xffff0000u),  msk, x[1]);
    x[2] = fmaf(__uint_as_float(v.y << 16),          msk, x[2]);
    x[3] = fmaf(__uint_as_float(v.y & 0xffff0000u),  msk, x[3]);
    x[4] = fmaf(__uint_as_float(v.z << 16),          msk, x[4]);
    x[5] = fmaf(__uint_as_float(v.z & 0xffff0000u),  msk, x[5]);
    x[6] = fmaf(__uint_as_float(v.w << 16),          msk, x[6]);
    x[7] = fmaf(__uint_as_float(v.w & 0xffff0000u),  msk, x[7]);
}

// ---------------- prep: fill buckets (batched) + pack weights + nodes->bf16 ----
__global__ __launch_bounds__(256) void prep_k(
    const int* __restrict__ adj, int* __restrict__ cnt, unsigned short* __restrict__ slots,
    const float* __restrict__ Wr, const float* __restrict__ Wz,
    const float* __restrict__ Wt, unsigned short* __restrict__ wp,
    const float* __restrict__ nodes, unsigned short* __restrict__ nbf)
{
    int b = blockIdx.x;
    if (b < FILL_BLOCKS) {
        int t = b * 256 + threadIdx.x;
        int d[4], s[4], pos[4];
        bool vld[4];
        // coalesced strided loads of 4 edges
#pragma unroll
        for (int i = 0; i < 4; ++i) {
            int e = t + i * FILL_T;
            vld[i] = (e < NE);
            d[i] = vld[i] ? adj[e] : 0;
            s[i] = vld[i] ? adj[NE + e] : 0;
        }
        // 4 independent atomics in flight (padded counters: 1 line/node)
#pragma unroll
        for (int i = 0; i < 4; ++i)
            if (vld[i]) pos[i] = atomicAdd(&cnt[(size_t)d[i] * CSTR], 1);
        // then the scattered slot stores
#pragma unroll
        for (int i = 0; i < 4; ++i)
            if (vld[i] && pos[i] < CAP)
                slots[(size_t)d[i] * CAP + pos[i]] = (unsigned short)s[i];
        // pos >= CAP: cnt[d] > CAP signals fused_k to take the full-scan path
    } else if (b < FILL_BLOCKS + CONV_BLOCKS) {
        int t = (b - FILL_BLOCKS) * 256 + threadIdx.x;   // [0, 98304)
        int j  = t & 7;
        int l  = (t >> 3) & 63;
        int kt = (t >> 9) & 7;
        int ct = (t >> 12) & 7;
        int g  = t >> 15;
        int k   = kt * 32 + ((l >> 4) & 3) * 8 + j;
        int col = ct * 16 + (l & 15);
        const float* W = (g == 0) ? Wr : (g == 1) ? Wz : Wt;
        wp[t] = f2bf(W[k * DD + col]);
    } else {
        int t = (b - FILL_BLOCKS - CONV_BLOCKS) * 256 + threadIdx.x;  // [0, 800000)
        const float4* s4 = (const float4*)nodes + (size_t)t * 2;
        float4 a = s4[0], c4 = s4[1];
        uint4 o;
        o.x = (unsigned)f2bf(a.x)  | ((unsigned)f2bf(a.y)  << 16);
        o.y = (unsigned)f2bf(a.z)  | ((unsigned)f2bf(a.w)  << 16);
        o.z = (unsigned)f2bf(c4.x) | ((unsigned)f2bf(c4.y) << 16);
        o.w = (unsigned)f2bf(c4.z) | ((unsigned)f2bf(c4.w) << 16);
        ((uint4*)nbf)[t] = o;
    }
}

// ---------------- fused: pipelined gather -> softmax -> 3 MFMA GEMMs -> output ----
__global__ __launch_bounds__(256, 4) void fused_k(
    const unsigned short* __restrict__ nbf,
    const int* __restrict__ adj,
    const int* __restrict__ cnt,
    const unsigned short* __restrict__ slots,
    const unsigned short* __restrict__ wp,
    const float* __restrict__ bias,
    const float* __restrict__ br, const float* __restrict__ bz, const float* __restrict__ bt,
    float* __restrict__ out)
{
    // X[row][0:128]=s (bf16) -> later r*ph; X[row][128:256]=ph (bf16, kept); +8 pad
    __shared__ unsigned short X[64][264];       // 33.8 KB (only LDS array)
    const int tid  = threadIdx.x;
    const int w    = tid >> 6;                  // wave id: owns rows w*16..w*16+15
    const int l    = tid & 63;
    const int row0 = blockIdx.x * 64;
    const int q    = l >> 4;                    // quarter-wave id
    const int li   = l & 15;                    // lane in quarter: channels 8li..8li+7

    // ---- Phase A: 2-deep pipelined gather + softmax, stage bf16 [s|ph] in LDS
    {
        const float4 bb0 = *(const float4*)(bias + 8 * li);
        const float4 bb1 = *(const float4*)(bias + 8 * li + 4);
        int rown  = row0 + (w << 4) + li;
        int c_all = cnt[(size_t)(rown < NN ? rown : 0) * CSTR];

        unsigned short sraw[2];                 // pending slot loads (rows j+1, j+2)
        uint4 vg[2][4]; float mg[2][4];         // pending gathers (rows j, j+1)
        uint4 phg[2];                           // pending ph loads
        int   slotm[2], cj[2];

        // prologue: slot loads for rows 0,1; gathers for row 0
        {
            int g0 = row0 + (w << 4);
            int gc0 = g0 < NN ? g0 : 0;
            int gc1 = (g0 + 1) < NN ? (g0 + 1) : 0;
            sraw[0] = slots[(size_t)gc0 * CAP + l];
            sraw[1] = slots[(size_t)gc1 * CAP + l];
            cj[0] = __shfl(c_all, 0);
            slotm[0] = (l < cj[0]) ? (int)sraw[0] : 0;
            if (q == 1) phg[0] = *(const uint4*)(nbf + (size_t)gc0 * DD + 8 * li);
#pragma unroll
            for (int i = 0; i < 4; ++i) {
                int sp = i * 4 + q;
                int s0 = __shfl(slotm[0], sp);
                vg[0][i] = *(const uint4*)(nbf + (size_t)s0 * DD + 8 * li);
                mg[0][i] = (sp < cj[0]) ? 1.f : 0.f;
            }
        }

#pragma unroll
        for (int j = 0; j < 16; ++j) {
            const int p = j & 1, pn = p ^ 1;
            // issue slot load for row j+2
            unsigned short snew = 0;
            if (j + 2 < 16) {
                int g2 = row0 + (w << 4) + j + 2;
                int gc2 = g2 < NN ? g2 : 0;
                snew = slots[(size_t)gc2 * CAP + l];
            }
            // issue gathers for row j+1 (slot load issued 2 iters ago)
            if (j + 1 < 16) {
                int g1 = row0 + (w << 4) + j + 1;
                int gc1 = g1 < NN ? g1 : 0;
                cj[pn] = __shfl(c_all, j + 1);
                slotm[pn] = (l < cj[pn]) ? (int)sraw[pn] : 0;
                if (q == 1) phg[pn] = *(const uint4*)(nbf + (size_t)gc1 * DD + 8 * li);
#pragma unroll
                for (int i = 0; i < 4; ++i) {
                    int sp = i * 4 + q;
                    int s0 = __shfl(slotm[pn], sp);
                    vg[pn][i] = *(const uint4*)(nbf + (size_t)s0 * DD + 8 * li);
                    mg[pn][i] = (sp < cj[pn]) ? 1.f : 0.f;
                }
            }
            // ---- combine row j
            int lr   = (w << 4) + j;
            int grow = row0 + lr;
            int c    = cj[p];
            float x[8];
#pragma unroll
            for (int i = 0; i < 8; ++i) x[i] = 0.f;
            if (c <= CAP) {
#pragma unroll
                for (int i = 0; i < 4; ++i) accum8(x, vg[p][i], mg[p][i]);
                for (int jj = 16; jj < c; jj += 16) {        // deg>16 tail (~10% rows)
                    uint4 v[4]; float msk[4];
#pragma unroll
                    for (int i = 0; i < 4; ++i) {
                        int sp = jj + i * 4 + q;
                        int s0 = __shfl(slotm[p], sp & 63);
                        v[i] = *(const uint4*)(nbf + (size_t)s0 * DD + 8 * li);
                        msk[i] = (sp < c) ? 1.f : 0.f;
                    }
#pragma unroll
                    for (int i = 0; i < 4; ++i) accum8(x, v[i], msk[i]);
                }
            } else {
                // overflow (prob ~0): full edge scan, matches round-robin over quarters
                int mi = 0;
                for (int base = 0; base < NE; base += 64) {
                    int e  = base + l;
                    int d  = (e < NE) ? adj[e] : -1;
                    int sv = (e < NE) ? adj[NE + e] : 0;
                    unsigned long long m = __ballot(d == grow);
                    while (m) {
                        int bpos = __ffsll((unsigned long long)m) - 1;
                        m &= m - 1;
                        int s0 = __shfl(sv, bpos);
                        if ((mi & 3) == q) {
                            uint4 v = *(const uint4*)(nbf + (size_t)s0 * DD + 8 * li);
                            accum8(x, v, 1.f);
                        }
                        ++mi;
                    }
                }
            }
            // combine quarter partial sums, add bias
#pragma unroll
            for (int i = 0; i < 8; ++i) {
                x[i] += __shfl_xor(x[i], 16);
                x[i] += __shfl_xor(x[i], 32);
            }
            x[0] += bb0.x; x[1] += bb0.y; x[2] += bb0.z; x[3] += bb0.w;
            x[4] += bb1.x; x[5] += bb1.y; x[6] += bb1.z; x[7] += bb1.w;
            // softmax over 128 channels (8/lane x 16 lanes, replicated across quarters)
            float mx = x[0];
#pragma unroll
            for (int i = 1; i < 8; ++i) mx = fmaxf(mx, x[i]);
#pragma unroll
            for (int o = 1; o < 16; o <<= 1) mx = fmaxf(mx, __shfl_xor(mx, o));
            float e8[8], sm = 0.f;
#pragma unroll
            for (int i = 0; i < 8; ++i) { e8[i] = __expf(x[i] - mx); sm += e8[i]; }
#pragma unroll
            for (int o = 1; o < 16; o <<= 1) sm += __shfl_xor(sm, o);
            float inv = 1.f / sm;
            if (q == 0) {
                uint4 u;
                u.x = (unsigned)f2bf(e8[0] * inv) | ((unsigned)f2bf(e8[1] * inv) << 16);
                u.y = (unsigned)f2bf(e8[2] * inv) | ((unsigned)f2bf(e8[3] * inv) << 16);
                u.z = (unsigned)f2bf(e8[4] * inv) | ((unsigned)f2bf(e8[5] * inv) << 16);
                u.w = (unsigned)f2bf(e8[6] * inv) | ((unsigned)f2bf(e8[7] * inv) << 16);
                *(uint4*)&X[lr][8 * li] = u;
            } else if (q == 1) {
                *(uint4*)&X[lr][128 + 8 * li] = phg[p];
            }
            sraw[p] = snew;     // row j+2 has parity p
        }
    }
    // NO __syncthreads: each wave reads only the 16 rows it just wrote.

    // ---- Phase B: MFMA GEMMs. Wave w owns row tile rt=w.
    const int rbase  = w * 16;
    const int mrow   = l & 15;      // A-frag row within tile
    const int quad   = l >> 4;      // A/B-frag k-quad
    const int col_in = l & 15;      // C/D col within tile
    const int rq     = l >> 4;      // C/D row quad

    s16x8 a[8];                      // A-frags for K=256 (8 x 32)
#pragma unroll
    for (int kt = 0; kt < 8; ++kt)
        a[kt] = *(const s16x8*)&X[rbase + mrow][kt * 32 + quad * 8];

    const s16x8* wp8 = (const s16x8*)wp;
    float zv[8][4];

    // r and z over all 8 col-tiles; write r*ph into the (dead) s-half of X,
    // preserving original ph in the ph-half for the epilogue.
#pragma unroll
    for (int ct = 0; ct < 8; ++ct) {
        int c = ct * 16 + col_in;
        float brv = br[c], bzv = bz[c];
        f32x4 ar = {brv, brv, brv, brv};
        f32x4 az = {bzv, bzv, bzv, bzv};
#pragma unroll
        for (int kt = 0; kt < 8; ++kt) {
            s16x8 bfr = wp8[((0 * 8 + ct) * 8 + kt) * 64 + l];
            s16x8 bfz = wp8[((1 * 8 + ct) * 8 + kt) * 64 + l];
            ar = __builtin_amdgcn_mfma_f32_16x16x32_bf16(a[kt], bfr, ar, 0, 0, 0);
            az = __builtin_amdgcn_mfma_f32_16x16x32_bf16(a[kt], bfz, az, 0, 0, 0);
        }
#pragma unroll
        for (int i = 0; i < 4; ++i) {
            float rr = 1.f / (1.f + __expf(-ar[i]));
            zv[ct][i] = 1.f / (1.f + __expf(-az[i]));
            int lr = rbase + rq * 4 + i;
            float ph = bf2f(X[lr][128 + c]);
            X[lr][c] = f2bf(rr * ph);             // same-wave rows only; s-half is dead
        }
    }

    // reload A-frags kt=4..7 (r*ph) from the s-half
#pragma unroll
    for (int kt = 4; kt < 8; ++kt)
        a[kt] = *(const s16x8*)&X[rbase + mrow][(kt - 4) * 32 + quad * 8];

    // t GEMM + epilogue
#pragma unroll
    for (int ct = 0; ct < 8; ++ct) {
        int c = ct * 16 + col_in;
        float btv = bt[c];
        f32x4 at = {btv, btv, btv, btv};
#pragma unroll
        for (int kt = 0; kt < 8; ++kt) {
            s16x8 bft = wp8[((2 * 8 + ct) * 8 + kt) * 64 + l];
            at = __builtin_amdgcn_mfma_f32_16x16x32_bf16(a[kt], bft, at, 0, 0, 0);
        }
#pragma unroll
        for (int i = 0; i < 4; ++i) {
            int lr   = rbase + rq * 4 + i;
            int grow = row0 + lr;
            if (grow < NN) {
                float hh = tanhf(at[i]);
                float z  = zv[ct][i];
                float ph = bf2f(X[lr][128 + c]);  // original ph (bf16), preserved
                out[(size_t)grow * DD + c] = (1.f - z) * ph + z * hh;
            }
        }
    }
}

extern "C" void kernel_launch(void* const* d_in, const int* in_sizes, int n_in,
                              void* d_out, int out_size, void* d_ws, size_t ws_size,
                              hipStream_t stream) {
    const float* nodes = (const float*)d_in[0];
    const int*   adj   = (const int*)d_in[1];
    const float* bias  = (const float*)d_in[2];
    const float* Wr    = (const float*)d_in[3];
    const float* br    = (const float*)d_in[4];
    const float* Wz    = (const float*)d_in[5];
    const float* bz    = (const float*)d_in[6];
    const float* Wt    = (const float*)d_in[7];
    const float* bt    = (const float*)d_in[8];
    float* out = (float*)d_out;

    char* ws = (char*)d_ws;
    int*            cnt   = (int*)ws;
    unsigned short* slots = (unsigned short*)(ws + SLOT_OFF);
    unsigned short* wpack = (unsigned short*)(ws + WPACK_OFF);
    unsigned short* nbf   = (unsigned short*)(ws + NBF_OFF);

    hipMemsetAsync(cnt, 0, CNT_BYTES, stream);

    // Reference never updates prior_h inside its loop -> all 4 steps identical;
    // one propagation step suffices.
    prep_k<<<FILL_BLOCKS + CONV_BLOCKS + NBF_BLOCKS, 256, 0, stream>>>(
        adj, cnt, slots, Wr, Wz, Wt, wpack, nodes, nbf);
    fused_k<<<(NN + 63) / 64, 256, 0, stream>>>(nbf, adj, cnt, slots, wpack,
                                                bias, br, bz, bt, out);
}